// Round 1
// baseline (937.583 us; speedup 1.0000x reference)
//
#include <hip/hip_runtime.h>

// EvidentialGNN: 2-layer GCN on fixed graph.
// evidence = softplus(gcn2(relu(gcn1(x)))), outputs (evidence[50000,64], h[50000,256]).

#define N_NODES 50000
#define N_EDGES_MAX 800000
#define IN_DIM 512
#define HID 256
#define NCLS 64

__global__ void init_kernel(int* __restrict__ cnt, int* __restrict__ cursor, int n) {
    int i = blockIdx.x * blockDim.x + threadIdx.x;
    if (i < n) { cnt[i] = 0; cursor[i] = 0; }
}

__global__ void count_kernel(const int* __restrict__ dst, int* __restrict__ cnt, int E) {
    int e = blockIdx.x * blockDim.x + threadIdx.x;
    if (e < E) atomicAdd(&cnt[dst[e]], 1);
}

// Single-block exclusive scan over n counts -> row_ptr[0..n], plus dinv = rsqrt(cnt+1).
__global__ __launch_bounds__(1024) void scan_kernel(const int* __restrict__ cnt,
                                                    int* __restrict__ row_ptr,
                                                    float* __restrict__ dinv, int n) {
    __shared__ int sums[1024];
    int tid = threadIdx.x;
    int chunk = (n + 1023) / 1024;
    int beg = tid * chunk;
    int end = min(beg + chunk, n);
    int s = 0;
    for (int i = beg; i < end; i++) s += cnt[i];
    sums[tid] = s;
    __syncthreads();
    // Hillis-Steele inclusive scan of per-thread sums
    for (int off = 1; off < 1024; off <<= 1) {
        int add = (tid >= off) ? sums[tid - off] : 0;
        __syncthreads();
        sums[tid] += add;
        __syncthreads();
    }
    int run = (tid == 0) ? 0 : sums[tid - 1];
    for (int i = beg; i < end; i++) {
        row_ptr[i] = run;
        int c = cnt[i];
        run += c;
        dinv[i] = rsqrtf((float)(c + 1));  // +1 self-loop; deg>=1 always
    }
    if (tid == 0) row_ptr[n] = sums[1023];
}

__global__ void fill_kernel(const int* __restrict__ src, const int* __restrict__ dst,
                            const int* __restrict__ row_ptr, int* __restrict__ cursor,
                            int* __restrict__ csr_src, int E) {
    int e = blockIdx.x * blockDim.x + threadIdx.x;
    if (e >= E) return;
    int d = dst[e];
    int pos = row_ptr[d] + atomicAdd(&cursor[d], 1);
    csr_src[pos] = src[e];
}

// Simple fp32 LDS-tiled GEMM: C[M,N] = A[M,K] @ B[K,N]. BM=BN=64, BK=16, 256 thr, 4x4/thr.
template <int BM, int BN, int BK, int TM, int TN>
__global__ __launch_bounds__(256) void gemm_kernel(const float* __restrict__ A,
                                                   const float* __restrict__ B,
                                                   float* __restrict__ C,
                                                   int M, int N, int K) {
    __shared__ float As[BK][BM + 1];
    __shared__ float Bs[BK][BN + 1];
    const int tid = threadIdx.x;
    const int tx = tid % (BN / TN);  // 16
    const int ty = tid / (BN / TN);  // 16
    const int row0 = blockIdx.y * BM;
    const int col0 = blockIdx.x * BN;
    float acc[TM][TN] = {};
    for (int k0 = 0; k0 < K; k0 += BK) {
        for (int i = tid; i < BM * BK; i += 256) {
            int r = i / BK, c = i % BK;
            int gr = row0 + r;
            As[c][r] = (gr < M) ? A[(long)gr * K + k0 + c] : 0.f;
        }
        for (int i = tid; i < BK * BN; i += 256) {
            int r = i / BN, c = i % BN;
            Bs[r][c] = B[(long)(k0 + r) * N + col0 + c];
        }
        __syncthreads();
#pragma unroll
        for (int kk = 0; kk < BK; kk++) {
            float a[TM], b[TN];
#pragma unroll
            for (int m = 0; m < TM; m++) a[m] = As[kk][ty * TM + m];
#pragma unroll
            for (int n = 0; n < TN; n++) b[n] = Bs[kk][tx * TN + n];
#pragma unroll
            for (int m = 0; m < TM; m++)
#pragma unroll
                for (int n = 0; n < TN; n++) acc[m][n] += a[m] * b[n];
        }
        __syncthreads();
    }
    for (int m = 0; m < TM; m++) {
        int gr = row0 + ty * TM + m;
        if (gr < M) {
            for (int n = 0; n < TN; n++) C[(long)gr * N + col0 + tx * TN + n] = acc[m][n];
        }
    }
}

// One wave per node. FPL = features per lane (FEAT = FPL*64). ACT: 0=relu, 1=softplus.
// out[i] = act( dinv[i]*( sum_{s in nbr(i)} dinv[s]*t[s] + dinv[i]*t[i] ) + bias )
template <int FPL, int ACT>
__global__ __launch_bounds__(256) void agg_kernel(const float* __restrict__ t,
                                                  const int* __restrict__ row_ptr,
                                                  const int* __restrict__ csr_src,
                                                  const float* __restrict__ dinv,
                                                  const float* __restrict__ bias,
                                                  float* __restrict__ out, int n) {
    const int FEAT = FPL * 64;
    int node = (blockIdx.x * blockDim.x + threadIdx.x) >> 6;
    int lane = threadIdx.x & 63;
    if (node >= n) return;
    float acc[FPL];
#pragma unroll
    for (int j = 0; j < FPL; j++) acc[j] = 0.f;
    const int beg = row_ptr[node], end = row_ptr[node + 1];
    for (int e = beg; e < end; e++) {
        int s = csr_src[e];
        float w = dinv[s];
        const float* rp = t + (long)s * FEAT + lane * FPL;
#pragma unroll
        for (int j = 0; j < FPL; j++) acc[j] += w * rp[j];
    }
    const float di = dinv[node];
    const float* sp = t + (long)node * FEAT + lane * FPL;
    float* op = out + (long)node * FEAT + lane * FPL;
#pragma unroll
    for (int j = 0; j < FPL; j++) {
        float r = di * (acc[j] + di * sp[j]) + bias[lane * FPL + j];
        if (ACT == 0) {
            r = fmaxf(r, 0.f);
        } else {
            r = fmaxf(r, 0.f) + log1pf(expf(-fabsf(r)));  // stable softplus
        }
        op[j] = r;
    }
}

extern "C" void kernel_launch(void* const* d_in, const int* in_sizes, int n_in,
                              void* d_out, int out_size, void* d_ws, size_t ws_size,
                              hipStream_t stream) {
    const float* x  = (const float*)d_in[0];
    const int*   ei = (const int*)d_in[1];
    const float* W1 = (const float*)d_in[2];
    const float* b1 = (const float*)d_in[3];
    const float* W2 = (const float*)d_in[4];
    const float* b2 = (const float*)d_in[5];

    float* evidence = (float*)d_out;                          // [50000, 64]
    float* h        = (float*)d_out + (long)N_NODES * NCLS;   // [50000, 256]

    const int E = in_sizes[1] / 2;
    const int* src = ei;
    const int* dst = ei + E;

    // Workspace carve-up (all 4-byte elements)
    int*   cnt     = (int*)d_ws;
    int*   cursor  = cnt + 50048;
    int*   row_ptr = cursor + 50048;             // 50001 used
    float* dinv    = (float*)(row_ptr + 50064);
    int*   csr_src = (int*)(dinv + 50048);       // E used
    float* t1      = (float*)(csr_src + N_EDGES_MAX);  // [50000, 256]
    float* t2      = t1 + (long)N_NODES * HID;         // [50000, 64]

    // --- Graph prep ---
    init_kernel<<<(N_NODES + 255) / 256, 256, 0, stream>>>(cnt, cursor, N_NODES);
    count_kernel<<<(E + 255) / 256, 256, 0, stream>>>(dst, cnt, E);
    scan_kernel<<<1, 1024, 0, stream>>>(cnt, row_ptr, dinv, N_NODES);
    fill_kernel<<<(E + 255) / 256, 256, 0, stream>>>(src, dst, row_ptr, cursor, csr_src, E);

    // --- Layer 1: t1 = x @ W1 ; h = relu(agg(t1) + b1) ---
    {
        dim3 grid(HID / 64, (N_NODES + 63) / 64);
        gemm_kernel<64, 64, 16, 4, 4><<<grid, 256, 0, stream>>>(x, W1, t1, N_NODES, HID, IN_DIM);
    }
    agg_kernel<4, 0><<<(N_NODES * 64 + 255) / 256, 256, 0, stream>>>(
        t1, row_ptr, csr_src, dinv, b1, h, N_NODES);

    // --- Layer 2: t2 = h @ W2 ; evidence = softplus(agg(t2) + b2) ---
    {
        dim3 grid(NCLS / 64, (N_NODES + 63) / 64);
        gemm_kernel<64, 64, 16, 4, 4><<<grid, 256, 0, stream>>>(h, W2, t2, N_NODES, NCLS, HID);
    }
    agg_kernel<1, 1><<<(N_NODES * 64 + 255) / 256, 256, 0, stream>>>(
        t2, row_ptr, csr_src, dinv, b2, evidence, N_NODES);
}

// Round 2
// 576.001 us; speedup vs baseline: 1.6277x; 1.6277x over previous
//
#include <hip/hip_runtime.h>

// EvidentialGNN: 2-layer GCN. evidence = softplus(gcn2(relu(gcn1(x)))).
// Outputs concatenated: (evidence[50000,64], h[50000,256]).
// R2: bf16 MFMA GEMMs (16x16x32) + bf16 intermediates to halve agg gather bytes.

#define N_NODES 50000
#define IN_DIM 512
#define HID 256
#define NCLS 64

typedef unsigned short u16;
typedef unsigned int u32;
typedef __attribute__((ext_vector_type(8))) short short8;
typedef __attribute__((ext_vector_type(4))) float float4_t;

__device__ __forceinline__ float bf_lo(u32 v) {  // low 16 bits are a bf16
    u32 u = v << 16; float f; __builtin_memcpy(&f, &u, 4); return f;
}
__device__ __forceinline__ float bf_hi(u32 v) {  // high 16 bits are a bf16
    u32 u = v & 0xffff0000u; float f; __builtin_memcpy(&f, &u, 4); return f;
}
__device__ __forceinline__ u16 f2bf(float f) {   // RNE float->bf16
    u32 u; __builtin_memcpy(&u, &f, 4);
    return (u16)((u + 0x7fffu + ((u >> 16) & 1u)) >> 16);
}

// ---------------- graph prep ----------------
__global__ void init_kernel(int* __restrict__ cnt, int* __restrict__ cursor, int n) {
    int i = blockIdx.x * blockDim.x + threadIdx.x;
    if (i < n) { cnt[i] = 0; cursor[i] = 0; }
}

__global__ void count_kernel(const int* __restrict__ dst, int* __restrict__ cnt, int E) {
    int e = blockIdx.x * blockDim.x + threadIdx.x;
    if (e < E) atomicAdd(&cnt[dst[e]], 1);
}

__global__ __launch_bounds__(1024) void scan_kernel(const int* __restrict__ cnt,
                                                    int* __restrict__ row_ptr,
                                                    float* __restrict__ dinv, int n) {
    __shared__ int sums[1024];
    int tid = threadIdx.x;
    int chunk = (n + 1023) / 1024;
    int beg = tid * chunk;
    int end = min(beg + chunk, n);
    int s = 0;
    for (int i = beg; i < end; i++) s += cnt[i];
    sums[tid] = s;
    __syncthreads();
    for (int off = 1; off < 1024; off <<= 1) {
        int add = (tid >= off) ? sums[tid - off] : 0;
        __syncthreads();
        sums[tid] += add;
        __syncthreads();
    }
    int run = (tid == 0) ? 0 : sums[tid - 1];
    for (int i = beg; i < end; i++) {
        row_ptr[i] = run;
        int c = cnt[i];
        run += c;
        dinv[i] = rsqrtf((float)(c + 1));  // +1 self-loop
    }
    if (tid == 0) row_ptr[n] = sums[1023];
}

__global__ void fill_kernel(const int* __restrict__ src, const int* __restrict__ dst,
                            const int* __restrict__ row_ptr, int* __restrict__ cursor,
                            int* __restrict__ csr_src, int E) {
    int e = blockIdx.x * blockDim.x + threadIdx.x;
    if (e >= E) return;
    int d = dst[e];
    int pos = row_ptr[d] + atomicAdd(&cursor[d], 1);
    csr_src[pos] = src[e];
}

// ---------------- casts ----------------
__global__ __launch_bounds__(256) void cast_bf16_kernel(const float* __restrict__ in,
                                                        u16* __restrict__ out, int n4) {
    int i = blockIdx.x * 256 + threadIdx.x;
    if (i >= n4) return;
    float4 v = ((const float4*)in)[i];
    ushort4 o = make_ushort4(f2bf(v.x), f2bf(v.y), f2bf(v.z), f2bf(v.w));
    ((ushort4*)out)[i] = o;
}

// Wt[n][k] = bf16(W[k][n]);  W is [K,N] row-major, Wt is [N,K] row-major.
__global__ __launch_bounds__(256) void tcast_kernel(const float* __restrict__ W,
                                                    u16* __restrict__ Wt, int K, int N) {
    int idx = blockIdx.x * 256 + threadIdx.x;
    if (idx >= K * N) return;
    int n = idx / K, k = idx - n * K;
    Wt[idx] = f2bf(W[k * N + n]);
}

// ---------------- bf16 MFMA GEMM ----------------
// C[M,N] = A[M,K] @ Bt[N,K]^T, all bf16 (stored as u16), C bf16, fp32 accumulate.
// Block: 256 threads = 4 waves, each wave computes 64x64 (4x4 of 16x16x32 MFMA).
// BK=32 elements (64 B per row). LDS tiles K-contiguous, staged via global_load_lds x16.
template <int BM, int BN, int K, int N>
__global__ __launch_bounds__(256) void mfma_gemm_kernel(const u16* __restrict__ A,
                                                        const u16* __restrict__ Bt,
                                                        u16* __restrict__ C, int M) {
    constexpr int WCOLS = (BN >= 128) ? 2 : 1;
    constexpr int WROWS = 4 / WCOLS;
    static_assert(WROWS * 64 == BM && WCOLS * 64 == BN, "wave tiling mismatch");
    constexpr int LDSA = BM * 32;  // u16 elements (row = 32 u16 = 64 B)
    __shared__ u16 lds[LDSA + BN * 32];

    const int tid = threadIdx.x;
    const int wave = tid >> 6, lane = tid & 63;
    const int wm = wave / WCOLS, wn = wave % WCOLS;
    const int quad = lane >> 4, l15 = lane & 15;
    const int row0 = blockIdx.y * BM;
    const int col0 = blockIdx.x * BN;

    float4_t acc[4][4];
#pragma unroll
    for (int mi = 0; mi < 4; mi++)
#pragma unroll
        for (int ni = 0; ni < 4; ni++) {
            float4_t z = {0.f, 0.f, 0.f, 0.f};
            acc[mi][ni] = z;
        }

    for (int k0 = 0; k0 < K; k0 += 32) {
        // stage A tile: BM rows x 64 B, 16 B chunks, contiguous per wave
#pragma unroll
        for (int i = 0; i < BM / 64; i++) {
            int c = tid + i * 256;          // chunk id
            int r = c >> 2;                 // tile row
            int gr = row0 + r;
            gr = gr < M ? gr : M - 1;       // clamp (dup loads, rows masked at store)
            const u16* gp = A + (long)gr * K + k0 + (c & 3) * 8;
            u16* lp = lds + c * 8;
            __builtin_amdgcn_global_load_lds((const __attribute__((address_space(1))) u32*)gp,
                                             (__attribute__((address_space(3))) u32*)lp,
                                             16, 0, 0);
        }
        // stage B tile: BN rows x 64 B
#pragma unroll
        for (int i = 0; i < BN / 64; i++) {
            int c = tid + i * 256;
            int r = c >> 2;
            const u16* gp = Bt + (long)(col0 + r) * K + k0 + (c & 3) * 8;
            u16* lp = lds + LDSA + c * 8;
            __builtin_amdgcn_global_load_lds((const __attribute__((address_space(1))) u32*)gp,
                                             (__attribute__((address_space(3))) u32*)lp,
                                             16, 0, 0);
        }
        __syncthreads();

        short8 af[4], bfr[4];
#pragma unroll
        for (int mi = 0; mi < 4; mi++)
            af[mi] = *(const short8*)(lds + (wm * 64 + mi * 16 + l15) * 32 + quad * 8);
#pragma unroll
        for (int ni = 0; ni < 4; ni++)
            bfr[ni] = *(const short8*)(lds + LDSA + (wn * 64 + ni * 16 + l15) * 32 + quad * 8);
#pragma unroll
        for (int mi = 0; mi < 4; mi++)
#pragma unroll
            for (int ni = 0; ni < 4; ni++)
                acc[mi][ni] = __builtin_amdgcn_mfma_f32_16x16x32_bf16(af[mi], bfr[ni],
                                                                      acc[mi][ni], 0, 0, 0);
        __syncthreads();
    }

    // epilogue: D[row=quad*4+r][col=l15] per 16x16 tile
#pragma unroll
    for (int mi = 0; mi < 4; mi++) {
#pragma unroll
        for (int r = 0; r < 4; r++) {
            int row = row0 + wm * 64 + mi * 16 + quad * 4 + r;
            if (row < M) {
#pragma unroll
                for (int ni = 0; ni < 4; ni++) {
                    int col = col0 + wn * 64 + ni * 16 + l15;
                    C[(long)row * N + col] = f2bf(acc[mi][ni][r]);
                }
            }
        }
    }
}

// ---------------- aggregation ----------------
// One wave per node, t is bf16 [n, FPL*64].
// out = act( dinv[i]*(sum_s dinv[s]*t[s] + dinv[i]*t[i]) + bias )
template <int FPL, int ACT, int EMIT_BF>
__global__ __launch_bounds__(256) void agg_kernel(const u16* __restrict__ t,
                                                  const int* __restrict__ row_ptr,
                                                  const int* __restrict__ csr_src,
                                                  const float* __restrict__ dinv,
                                                  const float* __restrict__ bias,
                                                  float* __restrict__ out_f,
                                                  u16* __restrict__ out_bf, int n) {
    const int FEAT = FPL * 64;
    int node = (blockIdx.x * blockDim.x + threadIdx.x) >> 6;
    int lane = threadIdx.x & 63;
    if (node >= n) return;
    float acc[FPL] = {};
    const int beg = row_ptr[node], end = row_ptr[node + 1];
    for (int e = beg; e < end; e++) {
        int s = csr_src[e];
        float w = dinv[s];
        if (FPL == 4) {
            uint2 v = *(const uint2*)(t + (long)s * FEAT + lane * 4);
            acc[0] += w * bf_lo(v.x);
            acc[1] += w * bf_hi(v.x);
            acc[2] += w * bf_lo(v.y);
            acc[3] += w * bf_hi(v.y);
        } else {
            acc[0] += w * bf_lo((u32)t[(long)s * FEAT + lane]);
        }
    }
    const float di = dinv[node];
    float self[FPL];
    if (FPL == 4) {
        uint2 v = *(const uint2*)(t + (long)node * FEAT + lane * 4);
        self[0] = bf_lo(v.x); self[1] = bf_hi(v.x);
        self[2] = bf_lo(v.y); self[3] = bf_hi(v.y);
    } else {
        self[0] = bf_lo((u32)t[(long)node * FEAT + lane]);
    }
    long base = (long)node * FEAT + lane * FPL;
#pragma unroll
    for (int j = 0; j < FPL; j++) {
        float r = di * (acc[j] + di * self[j]) + bias[lane * FPL + j];
        if (ACT == 0) {
            r = fmaxf(r, 0.f);
        } else {
            r = fmaxf(r, 0.f) + log1pf(expf(-fabsf(r)));  // stable softplus
        }
        out_f[base + j] = r;
        if (EMIT_BF) out_bf[base + j] = f2bf(r);
    }
}

extern "C" void kernel_launch(void* const* d_in, const int* in_sizes, int n_in,
                              void* d_out, int out_size, void* d_ws, size_t ws_size,
                              hipStream_t stream) {
    const float* x  = (const float*)d_in[0];
    const int*   ei = (const int*)d_in[1];
    const float* W1 = (const float*)d_in[2];
    const float* b1 = (const float*)d_in[3];
    const float* W2 = (const float*)d_in[4];
    const float* b2 = (const float*)d_in[5];

    float* evidence = (float*)d_out;                        // [50000, 64]
    float* h        = (float*)d_out + (long)N_NODES * NCLS; // [50000, 256]

    const int E = in_sizes[1] / 2;
    const int* src = ei;
    const int* dst = ei + E;

    // workspace carve-up (16B-aligned regions)
    char* w = (char*)d_ws;
    int*   cnt     = (int*)w;  w += 50048 * 4;
    int*   cursor  = (int*)w;  w += 50048 * 4;
    int*   row_ptr = (int*)w;  w += 50064 * 4;
    float* dinv    = (float*)w; w += 50048 * 4;
    int*   csr_src = (int*)w;  w += 800000 * 4;
    u16*   xbf     = (u16*)w;  w += (long)N_NODES * IN_DIM * 2;  // later reused as h_bf
    u16*   w1t     = (u16*)w;  w += IN_DIM * HID * 2;
    u16*   w2t     = (u16*)w;  w += HID * NCLS * 2;
    u16*   t1bf    = (u16*)w;  w += (long)N_NODES * HID * 2;     // later reused as t2_bf
    u16*   hbf     = xbf;   // alias: x_bf dead after GEMM1
    u16*   t2bf    = t1bf;  // alias: t1_bf dead after agg1

    // graph prep
    init_kernel<<<(N_NODES + 255) / 256, 256, 0, stream>>>(cnt, cursor, N_NODES);
    count_kernel<<<(E + 255) / 256, 256, 0, stream>>>(dst, cnt, E);
    scan_kernel<<<1, 1024, 0, stream>>>(cnt, row_ptr, dinv, N_NODES);
    fill_kernel<<<(E + 255) / 256, 256, 0, stream>>>(src, dst, row_ptr, cursor, csr_src, E);

    // casts
    cast_bf16_kernel<<<(N_NODES * IN_DIM / 4 + 255) / 256, 256, 0, stream>>>(
        x, xbf, N_NODES * IN_DIM / 4);
    tcast_kernel<<<(IN_DIM * HID + 255) / 256, 256, 0, stream>>>(W1, w1t, IN_DIM, HID);
    tcast_kernel<<<(HID * NCLS + 255) / 256, 256, 0, stream>>>(W2, w2t, HID, NCLS);

    // layer 1: t1 = x @ W1 (bf16 MFMA); h = relu(agg(t1) + b1), also h_bf
    {
        dim3 grid(HID / 128, (N_NODES + 127) / 128);
        mfma_gemm_kernel<128, 128, IN_DIM, HID><<<grid, 256, 0, stream>>>(xbf, w1t, t1bf, N_NODES);
    }
    agg_kernel<4, 0, 1><<<(N_NODES * 64 + 255) / 256, 256, 0, stream>>>(
        t1bf, row_ptr, csr_src, dinv, b1, h, hbf, N_NODES);

    // layer 2: t2 = h @ W2 (bf16 MFMA); evidence = softplus(agg(t2) + b2)
    {
        dim3 grid(NCLS / 64, (N_NODES + 255) / 256);
        mfma_gemm_kernel<256, 64, HID, NCLS><<<grid, 256, 0, stream>>>(hbf, w2t, t2bf, N_NODES);
    }
    agg_kernel<1, 1, 0><<<(N_NODES * 64 + 255) / 256, 256, 0, stream>>>(
        t2bf, row_ptr, csr_src, dinv, b2, evidence, nullptr, N_NODES);
}

// Round 4
// 478.661 us; speedup vs baseline: 1.9588x; 1.2034x over previous
//
#include <hip/hip_runtime.h>

// EvidentialGNN: 2-layer GCN. evidence = softplus(gcn2(relu(gcn1(x)))).
// Outputs concatenated: (evidence[50000,64], h[50000,256]).
// R4: resubmit R3 (hierarchical scan) unchanged — R3 crash looked like infra flake;
//     minimal diff to disambiguate flaky vs deterministic.

#define N_NODES 50000
#define IN_DIM 512
#define HID 256
#define NCLS 64

typedef unsigned short u16;
typedef unsigned int u32;
typedef __attribute__((ext_vector_type(8))) short short8;
typedef __attribute__((ext_vector_type(4))) float float4_t;

__device__ __forceinline__ float bf_lo(u32 v) {
    u32 u = v << 16; float f; __builtin_memcpy(&f, &u, 4); return f;
}
__device__ __forceinline__ float bf_hi(u32 v) {
    u32 u = v & 0xffff0000u; float f; __builtin_memcpy(&f, &u, 4); return f;
}
__device__ __forceinline__ u16 f2bf(float f) {   // RNE float->bf16
    u32 u; __builtin_memcpy(&u, &f, 4);
    return (u16)((u + 0x7fffu + ((u >> 16) & 1u)) >> 16);
}

// ---------------- graph prep ----------------
__global__ void init_kernel(int* __restrict__ cnt, int* __restrict__ cursor, int n) {
    int i = blockIdx.x * blockDim.x + threadIdx.x;
    if (i < n) { cnt[i] = 0; cursor[i] = 0; }
}

__global__ void count_kernel(const int* __restrict__ dst, int* __restrict__ cnt, int E) {
    int e = blockIdx.x * blockDim.x + threadIdx.x;
    if (e < E) atomicAdd(&cnt[dst[e]], 1);
}

// s1: per-block reduce of cnt -> blocksum; fused dinv = rsqrt(cnt+1).
__global__ __launch_bounds__(256) void s1_kernel(const int* __restrict__ cnt,
                                                 int* __restrict__ blocksum,
                                                 float* __restrict__ dinv, int n) {
    int tid = threadIdx.x;
    int i = blockIdx.x * 256 + tid;
    int c = (i < n) ? cnt[i] : 0;
    if (i < n) dinv[i] = rsqrtf((float)(c + 1));  // +1 self-loop
    __shared__ int s[256];
    s[tid] = c;
    __syncthreads();
    for (int off = 128; off > 0; off >>= 1) {
        if (tid < off) s[tid] += s[tid + off];
        __syncthreads();
    }
    if (tid == 0) blocksum[blockIdx.x] = s[0];
}

// s2: single block scans the <=256 block sums -> exclusive block offsets.
__global__ __launch_bounds__(256) void s2_kernel(const int* __restrict__ blocksum,
                                                 int* __restrict__ blockoff, int nb) {
    int tid = threadIdx.x;
    int v = (tid < nb) ? blocksum[tid] : 0;
    __shared__ int s[256];
    s[tid] = v;
    __syncthreads();
    for (int off = 1; off < 256; off <<= 1) {
        int a = (tid >= off) ? s[tid - off] : 0;
        __syncthreads();
        s[tid] += a;
        __syncthreads();
    }
    blockoff[tid] = (tid == 0) ? 0 : s[tid - 1];
}

// s3: block-local exclusive scan + block offset -> row_ptr[0..n].
__global__ __launch_bounds__(256) void s3_kernel(const int* __restrict__ cnt,
                                                 const int* __restrict__ blockoff,
                                                 int* __restrict__ row_ptr, int n) {
    int tid = threadIdx.x;
    int i = blockIdx.x * 256 + tid;
    int c = (i < n) ? cnt[i] : 0;
    __shared__ int s[256];
    s[tid] = c;
    __syncthreads();
    for (int off = 1; off < 256; off <<= 1) {
        int a = (tid >= off) ? s[tid - off] : 0;
        __syncthreads();
        s[tid] += a;
        __syncthreads();
    }
    if (i <= n) row_ptr[i] = blockoff[blockIdx.x] + s[tid] - c;
}

__global__ void fill_kernel(const int* __restrict__ src, const int* __restrict__ dst,
                            const int* __restrict__ row_ptr, int* __restrict__ cursor,
                            int* __restrict__ csr_src, int E) {
    int e = blockIdx.x * blockDim.x + threadIdx.x;
    if (e >= E) return;
    int d = dst[e];
    int pos = row_ptr[d] + atomicAdd(&cursor[d], 1);
    csr_src[pos] = src[e];
}

// ---------------- casts ----------------
__global__ __launch_bounds__(256) void cast_bf16_kernel(const float* __restrict__ in,
                                                        u16* __restrict__ out, int n4) {
    int i = blockIdx.x * 256 + threadIdx.x;
    if (i >= n4) return;
    float4 v = ((const float4*)in)[i];
    ushort4 o = make_ushort4(f2bf(v.x), f2bf(v.y), f2bf(v.z), f2bf(v.w));
    ((ushort4*)out)[i] = o;
}

// Wt[n][k] = bf16(W[k][n]);  W is [K,N] row-major, Wt is [N,K] row-major.
__global__ __launch_bounds__(256) void tcast_kernel(const float* __restrict__ W,
                                                    u16* __restrict__ Wt, int K, int N) {
    int idx = blockIdx.x * 256 + threadIdx.x;
    if (idx >= K * N) return;
    int n = idx / K, k = idx - n * K;
    Wt[idx] = f2bf(W[k * N + n]);
}

// ---------------- bf16 MFMA GEMM ----------------
// C[M,N] = A[M,K] @ Bt[N,K]^T, all bf16 (u16), fp32 accumulate, bf16 out.
// 256 threads = 4 waves; per-wave 64x64 via 4x4 of 16x16x32 MFMA. BK=32.
template <int BM, int BN, int K, int N>
__global__ __launch_bounds__(256) void mfma_gemm_kernel(const u16* __restrict__ A,
                                                        const u16* __restrict__ Bt,
                                                        u16* __restrict__ C, int M) {
    constexpr int WCOLS = (BN >= 128) ? 2 : 1;
    constexpr int WROWS = 4 / WCOLS;
    static_assert(WROWS * 64 == BM && WCOLS * 64 == BN, "wave tiling mismatch");
    constexpr int LDSA = BM * 32;
    __shared__ u16 lds[LDSA + BN * 32];

    const int tid = threadIdx.x;
    const int wave = tid >> 6, lane = tid & 63;
    const int wm = wave / WCOLS, wn = wave % WCOLS;
    const int quad = lane >> 4, l15 = lane & 15;
    const int row0 = blockIdx.y * BM;
    const int col0 = blockIdx.x * BN;

    float4_t acc[4][4];
#pragma unroll
    for (int mi = 0; mi < 4; mi++)
#pragma unroll
        for (int ni = 0; ni < 4; ni++) {
            float4_t z = {0.f, 0.f, 0.f, 0.f};
            acc[mi][ni] = z;
        }

    for (int k0 = 0; k0 < K; k0 += 32) {
#pragma unroll
        for (int i = 0; i < BM / 64; i++) {
            int c = tid + i * 256;
            int r = c >> 2;
            int gr = row0 + r;
            gr = gr < M ? gr : M - 1;
            const u16* gp = A + (long)gr * K + k0 + (c & 3) * 8;
            u16* lp = lds + c * 8;
            __builtin_amdgcn_global_load_lds((const __attribute__((address_space(1))) u32*)gp,
                                             (__attribute__((address_space(3))) u32*)lp,
                                             16, 0, 0);
        }
#pragma unroll
        for (int i = 0; i < BN / 64; i++) {
            int c = tid + i * 256;
            int r = c >> 2;
            const u16* gp = Bt + (long)(col0 + r) * K + k0 + (c & 3) * 8;
            u16* lp = lds + LDSA + c * 8;
            __builtin_amdgcn_global_load_lds((const __attribute__((address_space(1))) u32*)gp,
                                             (__attribute__((address_space(3))) u32*)lp,
                                             16, 0, 0);
        }
        __syncthreads();

        short8 af[4], bfr[4];
#pragma unroll
        for (int mi = 0; mi < 4; mi++)
            af[mi] = *(const short8*)(lds + (wm * 64 + mi * 16 + l15) * 32 + quad * 8);
#pragma unroll
        for (int ni = 0; ni < 4; ni++)
            bfr[ni] = *(const short8*)(lds + LDSA + (wn * 64 + ni * 16 + l15) * 32 + quad * 8);
#pragma unroll
        for (int mi = 0; mi < 4; mi++)
#pragma unroll
            for (int ni = 0; ni < 4; ni++)
                acc[mi][ni] = __builtin_amdgcn_mfma_f32_16x16x32_bf16(af[mi], bfr[ni],
                                                                      acc[mi][ni], 0, 0, 0);
        __syncthreads();
    }

#pragma unroll
    for (int mi = 0; mi < 4; mi++) {
#pragma unroll
        for (int r = 0; r < 4; r++) {
            int row = row0 + wm * 64 + mi * 16 + quad * 4 + r;
            if (row < M) {
#pragma unroll
                for (int ni = 0; ni < 4; ni++) {
                    int col = col0 + wn * 64 + ni * 16 + l15;
                    C[(long)row * N + col] = f2bf(acc[mi][ni][r]);
                }
            }
        }
    }
}

// ---------------- aggregation ----------------
// One wave per node, t is bf16 [n, FPL*64].
template <int FPL, int ACT, int EMIT_BF>
__global__ __launch_bounds__(256) void agg_kernel(const u16* __restrict__ t,
                                                  const int* __restrict__ row_ptr,
                                                  const int* __restrict__ csr_src,
                                                  const float* __restrict__ dinv,
                                                  const float* __restrict__ bias,
                                                  float* __restrict__ out_f,
                                                  u16* __restrict__ out_bf, int n) {
    const int FEAT = FPL * 64;
    int node = (blockIdx.x * blockDim.x + threadIdx.x) >> 6;
    int lane = threadIdx.x & 63;
    if (node >= n) return;
    float acc[FPL] = {};
    const int beg = row_ptr[node], end = row_ptr[node + 1];
    for (int e = beg; e < end; e++) {
        int s = csr_src[e];
        float w = dinv[s];
        if (FPL == 4) {
            uint2 v = *(const uint2*)(t + (long)s * FEAT + lane * 4);
            acc[0] += w * bf_lo(v.x);
            acc[1] += w * bf_hi(v.x);
            acc[2] += w * bf_lo(v.y);
            acc[3] += w * bf_hi(v.y);
        } else {
            acc[0] += w * bf_lo((u32)t[(long)s * FEAT + lane]);
        }
    }
    const float di = dinv[node];
    float self[FPL];
    if (FPL == 4) {
        uint2 v = *(const uint2*)(t + (long)node * FEAT + lane * 4);
        self[0] = bf_lo(v.x); self[1] = bf_hi(v.x);
        self[2] = bf_lo(v.y); self[3] = bf_hi(v.y);
    } else {
        self[0] = bf_lo((u32)t[(long)node * FEAT + lane]);
    }
    long base = (long)node * FEAT + lane * FPL;
#pragma unroll
    for (int j = 0; j < FPL; j++) {
        float r = di * (acc[j] + di * self[j]) + bias[lane * FPL + j];
        if (ACT == 0) {
            r = fmaxf(r, 0.f);
        } else {
            r = fmaxf(r, 0.f) + log1pf(expf(-fabsf(r)));  // stable softplus
        }
        out_f[base + j] = r;
        if (EMIT_BF) out_bf[base + j] = f2bf(r);
    }
}

extern "C" void kernel_launch(void* const* d_in, const int* in_sizes, int n_in,
                              void* d_out, int out_size, void* d_ws, size_t ws_size,
                              hipStream_t stream) {
    const float* x  = (const float*)d_in[0];
    const int*   ei = (const int*)d_in[1];
    const float* W1 = (const float*)d_in[2];
    const float* b1 = (const float*)d_in[3];
    const float* W2 = (const float*)d_in[4];
    const float* b2 = (const float*)d_in[5];

    float* evidence = (float*)d_out;                        // [50000, 64]
    float* h        = (float*)d_out + (long)N_NODES * NCLS; // [50000, 256]

    const int E = in_sizes[1] / 2;
    const int* src = ei;
    const int* dst = ei + E;

    const int NB = (N_NODES + 255) / 256;  // 196 scan blocks

    // workspace carve-up (16B-aligned regions)
    char* w = (char*)d_ws;
    int*   cnt      = (int*)w;  w += 50048 * 4;
    int*   cursor   = (int*)w;  w += 50048 * 4;
    int*   row_ptr  = (int*)w;  w += 50064 * 4;
    float* dinv     = (float*)w; w += 50048 * 4;
    int*   blocksum = (int*)w;  w += 256 * 4;
    int*   blockoff = (int*)w;  w += 256 * 4;
    int*   csr_src  = (int*)w;  w += 800000 * 4;
    u16*   xbf      = (u16*)w;  w += (long)N_NODES * IN_DIM * 2;  // reused as h_bf
    u16*   w1t      = (u16*)w;  w += IN_DIM * HID * 2;
    u16*   w2t      = (u16*)w;  w += HID * NCLS * 2;
    u16*   t1bf     = (u16*)w;  w += (long)N_NODES * HID * 2;     // reused as t2_bf
    u16*   hbf      = xbf;
    u16*   t2bf     = t1bf;

    // graph prep
    init_kernel<<<NB, 256, 0, stream>>>(cnt, cursor, N_NODES);
    count_kernel<<<(E + 255) / 256, 256, 0, stream>>>(dst, cnt, E);
    s1_kernel<<<NB, 256, 0, stream>>>(cnt, blocksum, dinv, N_NODES);
    s2_kernel<<<1, 256, 0, stream>>>(blocksum, blockoff, NB);
    s3_kernel<<<NB, 256, 0, stream>>>(cnt, blockoff, row_ptr, N_NODES);
    fill_kernel<<<(E + 255) / 256, 256, 0, stream>>>(src, dst, row_ptr, cursor, csr_src, E);

    // casts
    cast_bf16_kernel<<<(N_NODES * IN_DIM / 4 + 255) / 256, 256, 0, stream>>>(
        x, xbf, N_NODES * IN_DIM / 4);
    tcast_kernel<<<(IN_DIM * HID + 255) / 256, 256, 0, stream>>>(W1, w1t, IN_DIM, HID);
    tcast_kernel<<<(HID * NCLS + 255) / 256, 256, 0, stream>>>(W2, w2t, HID, NCLS);

    // layer 1: t1 = x @ W1 (bf16 MFMA); h = relu(agg(t1) + b1), also h_bf
    {
        dim3 grid(HID / 128, (N_NODES + 127) / 128);
        mfma_gemm_kernel<128, 128, IN_DIM, HID><<<grid, 256, 0, stream>>>(xbf, w1t, t1bf, N_NODES);
    }
    agg_kernel<4, 0, 1><<<(N_NODES * 64 + 255) / 256, 256, 0, stream>>>(
        t1bf, row_ptr, csr_src, dinv, b1, h, hbf, N_NODES);

    // layer 2: t2 = h @ W2 (bf16 MFMA); evidence = softplus(agg(t2) + b2)
    {
        dim3 grid(NCLS / 64, (N_NODES + 255) / 256);
        mfma_gemm_kernel<256, 64, HID, NCLS><<<grid, 256, 0, stream>>>(hbf, w2t, t2bf, N_NODES);
    }
    agg_kernel<1, 1, 0><<<(N_NODES * 64 + 255) / 256, 256, 0, stream>>>(
        t2bf, row_ptr, csr_src, dinv, b2, evidence, nullptr, N_NODES);
}

// Round 5
// 459.412 us; speedup vs baseline: 2.0408x; 1.0419x over previous
//
#include <hip/hip_runtime.h>

// EvidentialGNN: 2-layer GCN. evidence = softplus(gcn2(relu(gcn1(x)))).
// Outputs concatenated: (evidence[50000,64], h[50000,256]).
// R5: latency-hiding aggregation — G edges in flight per wave, uint4 (16B/lane)
//     gathers, shfl_xor cross-group reduce. agg was 3.16 TB/s latency-bound.

#define N_NODES 50000
#define IN_DIM 512
#define HID 256
#define NCLS 64

typedef unsigned short u16;
typedef unsigned int u32;
typedef __attribute__((ext_vector_type(8))) short short8;
typedef __attribute__((ext_vector_type(4))) float float4_t;

__device__ __forceinline__ float bf_lo(u32 v) {
    u32 u = v << 16; float f; __builtin_memcpy(&f, &u, 4); return f;
}
__device__ __forceinline__ float bf_hi(u32 v) {
    u32 u = v & 0xffff0000u; float f; __builtin_memcpy(&f, &u, 4); return f;
}
__device__ __forceinline__ u16 f2bf(float f) {   // RNE float->bf16
    u32 u; __builtin_memcpy(&u, &f, 4);
    return (u16)((u + 0x7fffu + ((u >> 16) & 1u)) >> 16);
}
__device__ __forceinline__ void acc8(float* acc, uint4 v, float w) {
    acc[0] += w * bf_lo(v.x); acc[1] += w * bf_hi(v.x);
    acc[2] += w * bf_lo(v.y); acc[3] += w * bf_hi(v.y);
    acc[4] += w * bf_lo(v.z); acc[5] += w * bf_hi(v.z);
    acc[6] += w * bf_lo(v.w); acc[7] += w * bf_hi(v.w);
}

// ---------------- graph prep ----------------
__global__ void init_kernel(int* __restrict__ cnt, int* __restrict__ cursor, int n) {
    int i = blockIdx.x * blockDim.x + threadIdx.x;
    if (i < n) { cnt[i] = 0; cursor[i] = 0; }
}

__global__ void count_kernel(const int* __restrict__ dst, int* __restrict__ cnt, int E) {
    int e = blockIdx.x * blockDim.x + threadIdx.x;
    if (e < E) atomicAdd(&cnt[dst[e]], 1);
}

// s1: per-block reduce of cnt -> blocksum; fused dinv = rsqrt(cnt+1).
__global__ __launch_bounds__(256) void s1_kernel(const int* __restrict__ cnt,
                                                 int* __restrict__ blocksum,
                                                 float* __restrict__ dinv, int n) {
    int tid = threadIdx.x;
    int i = blockIdx.x * 256 + tid;
    int c = (i < n) ? cnt[i] : 0;
    if (i < n) dinv[i] = rsqrtf((float)(c + 1));  // +1 self-loop
    __shared__ int s[256];
    s[tid] = c;
    __syncthreads();
    for (int off = 128; off > 0; off >>= 1) {
        if (tid < off) s[tid] += s[tid + off];
        __syncthreads();
    }
    if (tid == 0) blocksum[blockIdx.x] = s[0];
}

// s2: single block scans the <=256 block sums -> exclusive block offsets.
__global__ __launch_bounds__(256) void s2_kernel(const int* __restrict__ blocksum,
                                                 int* __restrict__ blockoff, int nb) {
    int tid = threadIdx.x;
    int v = (tid < nb) ? blocksum[tid] : 0;
    __shared__ int s[256];
    s[tid] = v;
    __syncthreads();
    for (int off = 1; off < 256; off <<= 1) {
        int a = (tid >= off) ? s[tid - off] : 0;
        __syncthreads();
        s[tid] += a;
        __syncthreads();
    }
    blockoff[tid] = (tid == 0) ? 0 : s[tid - 1];
}

// s3: block-local exclusive scan + block offset -> row_ptr[0..n].
__global__ __launch_bounds__(256) void s3_kernel(const int* __restrict__ cnt,
                                                 const int* __restrict__ blockoff,
                                                 int* __restrict__ row_ptr, int n) {
    int tid = threadIdx.x;
    int i = blockIdx.x * 256 + tid;
    int c = (i < n) ? cnt[i] : 0;
    __shared__ int s[256];
    s[tid] = c;
    __syncthreads();
    for (int off = 1; off < 256; off <<= 1) {
        int a = (tid >= off) ? s[tid - off] : 0;
        __syncthreads();
        s[tid] += a;
        __syncthreads();
    }
    if (i <= n) row_ptr[i] = blockoff[blockIdx.x] + s[tid] - c;
}

__global__ void fill_kernel(const int* __restrict__ src, const int* __restrict__ dst,
                            const int* __restrict__ row_ptr, int* __restrict__ cursor,
                            int* __restrict__ csr_src, int E) {
    int e = blockIdx.x * blockDim.x + threadIdx.x;
    if (e >= E) return;
    int d = dst[e];
    int pos = row_ptr[d] + atomicAdd(&cursor[d], 1);
    csr_src[pos] = src[e];
}

// ---------------- casts ----------------
__global__ __launch_bounds__(256) void cast_bf16_kernel(const float* __restrict__ in,
                                                        u16* __restrict__ out, int n4) {
    int i = blockIdx.x * 256 + threadIdx.x;
    if (i >= n4) return;
    float4 v = ((const float4*)in)[i];
    ushort4 o = make_ushort4(f2bf(v.x), f2bf(v.y), f2bf(v.z), f2bf(v.w));
    ((ushort4*)out)[i] = o;
}

// Wt[n][k] = bf16(W[k][n]);  W is [K,N] row-major, Wt is [N,K] row-major.
__global__ __launch_bounds__(256) void tcast_kernel(const float* __restrict__ W,
                                                    u16* __restrict__ Wt, int K, int N) {
    int idx = blockIdx.x * 256 + threadIdx.x;
    if (idx >= K * N) return;
    int n = idx / K, k = idx - n * K;
    Wt[idx] = f2bf(W[k * N + n]);
}

// ---------------- bf16 MFMA GEMM ----------------
// C[M,N] = A[M,K] @ Bt[N,K]^T, all bf16 (u16), fp32 accumulate, bf16 out.
// 256 threads = 4 waves; per-wave 64x64 via 4x4 of 16x16x32 MFMA. BK=32.
template <int BM, int BN, int K, int N>
__global__ __launch_bounds__(256) void mfma_gemm_kernel(const u16* __restrict__ A,
                                                        const u16* __restrict__ Bt,
                                                        u16* __restrict__ C, int M) {
    constexpr int WCOLS = (BN >= 128) ? 2 : 1;
    constexpr int WROWS = 4 / WCOLS;
    static_assert(WROWS * 64 == BM && WCOLS * 64 == BN, "wave tiling mismatch");
    constexpr int LDSA = BM * 32;
    __shared__ u16 lds[LDSA + BN * 32];

    const int tid = threadIdx.x;
    const int wave = tid >> 6, lane = tid & 63;
    const int wm = wave / WCOLS, wn = wave % WCOLS;
    const int quad = lane >> 4, l15 = lane & 15;
    const int row0 = blockIdx.y * BM;
    const int col0 = blockIdx.x * BN;

    float4_t acc[4][4];
#pragma unroll
    for (int mi = 0; mi < 4; mi++)
#pragma unroll
        for (int ni = 0; ni < 4; ni++) {
            float4_t z = {0.f, 0.f, 0.f, 0.f};
            acc[mi][ni] = z;
        }

    for (int k0 = 0; k0 < K; k0 += 32) {
#pragma unroll
        for (int i = 0; i < BM / 64; i++) {
            int c = tid + i * 256;
            int r = c >> 2;
            int gr = row0 + r;
            gr = gr < M ? gr : M - 1;
            const u16* gp = A + (long)gr * K + k0 + (c & 3) * 8;
            u16* lp = lds + c * 8;
            __builtin_amdgcn_global_load_lds((const __attribute__((address_space(1))) u32*)gp,
                                             (__attribute__((address_space(3))) u32*)lp,
                                             16, 0, 0);
        }
#pragma unroll
        for (int i = 0; i < BN / 64; i++) {
            int c = tid + i * 256;
            int r = c >> 2;
            const u16* gp = Bt + (long)(col0 + r) * K + k0 + (c & 3) * 8;
            u16* lp = lds + LDSA + c * 8;
            __builtin_amdgcn_global_load_lds((const __attribute__((address_space(1))) u32*)gp,
                                             (__attribute__((address_space(3))) u32*)lp,
                                             16, 0, 0);
        }
        __syncthreads();

        short8 af[4], bfr[4];
#pragma unroll
        for (int mi = 0; mi < 4; mi++)
            af[mi] = *(const short8*)(lds + (wm * 64 + mi * 16 + l15) * 32 + quad * 8);
#pragma unroll
        for (int ni = 0; ni < 4; ni++)
            bfr[ni] = *(const short8*)(lds + LDSA + (wn * 64 + ni * 16 + l15) * 32 + quad * 8);
#pragma unroll
        for (int mi = 0; mi < 4; mi++)
#pragma unroll
            for (int ni = 0; ni < 4; ni++)
                acc[mi][ni] = __builtin_amdgcn_mfma_f32_16x16x32_bf16(af[mi], bfr[ni],
                                                                      acc[mi][ni], 0, 0, 0);
        __syncthreads();
    }

#pragma unroll
    for (int mi = 0; mi < 4; mi++) {
#pragma unroll
        for (int r = 0; r < 4; r++) {
            int row = row0 + wm * 64 + mi * 16 + quad * 4 + r;
            if (row < M) {
#pragma unroll
                for (int ni = 0; ni < 4; ni++) {
                    int col = col0 + wn * 64 + ni * 16 + l15;
                    C[(long)row * N + col] = f2bf(acc[mi][ni][r]);
                }
            }
        }
    }
}

// ---------------- aggregation (v2: G edges in flight per wave) ----------------
// One wave per node, t bf16 [n, FEAT]. LPE = FEAT/8 lanes cover one row with
// uint4 (16B) loads; G = 64/LPE edges processed concurrently; main loop is
// hand-unrolled x2 for 2G independent gather chains. Cross-group combine via
// shfl_xor butterfly; epilogue on first LPE lanes.
template <int FEAT, int ACT, int EMIT_BF>
__global__ __launch_bounds__(256) void agg_kernel(const u16* __restrict__ t,
                                                  const int* __restrict__ row_ptr,
                                                  const int* __restrict__ csr_src,
                                                  const float* __restrict__ dinv,
                                                  const float* __restrict__ bias,
                                                  float* __restrict__ out_f,
                                                  u16* __restrict__ out_bf, int n) {
    constexpr int LPE = FEAT / 8;  // lanes per edge row
    constexpr int G = 64 / LPE;    // concurrent edges per wave
    int node = (blockIdx.x * blockDim.x + threadIdx.x) >> 6;
    int lane = threadIdx.x & 63;
    if (node >= n) return;
    const int g = lane / LPE;
    const int r = lane % LPE;
    float acc[8] = {};
    const int beg = row_ptr[node], end = row_ptr[node + 1];
    int e = beg;
    for (; e + 2 * G <= end; e += 2 * G) {
        int s0 = csr_src[e + g];
        int s1 = csr_src[e + G + g];
        float w0 = dinv[s0], w1 = dinv[s1];
        uint4 v0 = *(const uint4*)(t + (long)s0 * FEAT + r * 8);
        uint4 v1 = *(const uint4*)(t + (long)s1 * FEAT + r * 8);
        acc8(acc, v0, w0);
        acc8(acc, v1, w1);
    }
    for (; e < end; e += G) {
        int ee = e + g;
        if (ee < end) {
            int s = csr_src[ee];
            float w = dinv[s];
            uint4 v = *(const uint4*)(t + (long)s * FEAT + r * 8);
            acc8(acc, v, w);
        }
    }
    // combine groups: after this every lane holds the full sum for its 8 feats
#pragma unroll
    for (int mask = LPE; mask < 64; mask <<= 1)
#pragma unroll
        for (int j = 0; j < 8; j++) acc[j] += __shfl_xor(acc[j], mask, 64);

    if (lane < LPE) {
        const float di = dinv[node];
        uint4 sv = *(const uint4*)(t + (long)node * FEAT + lane * 8);
        float self[8] = {bf_lo(sv.x), bf_hi(sv.x), bf_lo(sv.y), bf_hi(sv.y),
                         bf_lo(sv.z), bf_hi(sv.z), bf_lo(sv.w), bf_hi(sv.w)};
        float4 b0 = *(const float4*)(bias + lane * 8);
        float4 b1 = *(const float4*)(bias + lane * 8 + 4);
        float bb[8] = {b0.x, b0.y, b0.z, b0.w, b1.x, b1.y, b1.z, b1.w};
        float rv[8];
#pragma unroll
        for (int j = 0; j < 8; j++) {
            float v = di * (acc[j] + di * self[j]) + bb[j];
            if (ACT == 0) v = fmaxf(v, 0.f);
            else v = fmaxf(v, 0.f) + log1pf(expf(-fabsf(v)));  // stable softplus
            rv[j] = v;
        }
        long base = (long)node * FEAT + lane * 8;
        *(float4*)(out_f + base) = make_float4(rv[0], rv[1], rv[2], rv[3]);
        *(float4*)(out_f + base + 4) = make_float4(rv[4], rv[5], rv[6], rv[7]);
        if (EMIT_BF) {
            uint4 o;
            o.x = (u32)f2bf(rv[0]) | ((u32)f2bf(rv[1]) << 16);
            o.y = (u32)f2bf(rv[2]) | ((u32)f2bf(rv[3]) << 16);
            o.z = (u32)f2bf(rv[4]) | ((u32)f2bf(rv[5]) << 16);
            o.w = (u32)f2bf(rv[6]) | ((u32)f2bf(rv[7]) << 16);
            *(uint4*)(out_bf + base) = o;
        }
    }
}

extern "C" void kernel_launch(void* const* d_in, const int* in_sizes, int n_in,
                              void* d_out, int out_size, void* d_ws, size_t ws_size,
                              hipStream_t stream) {
    const float* x  = (const float*)d_in[0];
    const int*   ei = (const int*)d_in[1];
    const float* W1 = (const float*)d_in[2];
    const float* b1 = (const float*)d_in[3];
    const float* W2 = (const float*)d_in[4];
    const float* b2 = (const float*)d_in[5];

    float* evidence = (float*)d_out;                        // [50000, 64]
    float* h        = (float*)d_out + (long)N_NODES * NCLS; // [50000, 256]

    const int E = in_sizes[1] / 2;
    const int* src = ei;
    const int* dst = ei + E;

    const int NB = (N_NODES + 255) / 256;  // 196 scan blocks

    // workspace carve-up (16B-aligned regions)
    char* w = (char*)d_ws;
    int*   cnt      = (int*)w;  w += 50048 * 4;
    int*   cursor   = (int*)w;  w += 50048 * 4;
    int*   row_ptr  = (int*)w;  w += 50064 * 4;
    float* dinv     = (float*)w; w += 50048 * 4;
    int*   blocksum = (int*)w;  w += 256 * 4;
    int*   blockoff = (int*)w;  w += 256 * 4;
    int*   csr_src  = (int*)w;  w += 800000 * 4;
    u16*   xbf      = (u16*)w;  w += (long)N_NODES * IN_DIM * 2;  // reused as h_bf
    u16*   w1t      = (u16*)w;  w += IN_DIM * HID * 2;
    u16*   w2t      = (u16*)w;  w += HID * NCLS * 2;
    u16*   t1bf     = (u16*)w;  w += (long)N_NODES * HID * 2;     // reused as t2_bf
    u16*   hbf      = xbf;
    u16*   t2bf     = t1bf;

    // graph prep
    init_kernel<<<NB, 256, 0, stream>>>(cnt, cursor, N_NODES);
    count_kernel<<<(E + 255) / 256, 256, 0, stream>>>(dst, cnt, E);
    s1_kernel<<<NB, 256, 0, stream>>>(cnt, blocksum, dinv, N_NODES);
    s2_kernel<<<1, 256, 0, stream>>>(blocksum, blockoff, NB);
    s3_kernel<<<NB, 256, 0, stream>>>(cnt, blockoff, row_ptr, N_NODES);
    fill_kernel<<<(E + 255) / 256, 256, 0, stream>>>(src, dst, row_ptr, cursor, csr_src, E);

    // casts
    cast_bf16_kernel<<<(N_NODES * IN_DIM / 4 + 255) / 256, 256, 0, stream>>>(
        x, xbf, N_NODES * IN_DIM / 4);
    tcast_kernel<<<(IN_DIM * HID + 255) / 256, 256, 0, stream>>>(W1, w1t, IN_DIM, HID);
    tcast_kernel<<<(HID * NCLS + 255) / 256, 256, 0, stream>>>(W2, w2t, HID, NCLS);

    // layer 1: t1 = x @ W1 (bf16 MFMA); h = relu(agg(t1) + b1), also h_bf
    {
        dim3 grid(HID / 128, (N_NODES + 127) / 128);
        mfma_gemm_kernel<128, 128, IN_DIM, HID><<<grid, 256, 0, stream>>>(xbf, w1t, t1bf, N_NODES);
    }
    agg_kernel<HID, 0, 1><<<(N_NODES * 64 + 255) / 256, 256, 0, stream>>>(
        t1bf, row_ptr, csr_src, dinv, b1, h, hbf, N_NODES);

    // layer 2: t2 = h @ W2 (bf16 MFMA); evidence = softplus(agg(t2) + b2)
    {
        dim3 grid(NCLS / 64, (N_NODES + 255) / 256);
        mfma_gemm_kernel<256, 64, HID, NCLS><<<grid, 256, 0, stream>>>(hbf, w2t, t2bf, N_NODES);
    }
    agg_kernel<NCLS, 1, 0><<<(N_NODES * 64 + 255) / 256, 256, 0, stream>>>(
        t2bf, row_ptr, csr_src, dinv, b2, evidence, nullptr, N_NODES);
}

// Round 6
// 410.881 us; speedup vs baseline: 2.2819x; 1.1181x over previous
//
#include <hip/hip_runtime.h>

// EvidentialGNN: 2-layer GCN. evidence = softplus(gcn2(relu(gcn1(x)))).
// Outputs concatenated: (evidence[50000,64], h[50000,256]).
// R6: agg2 -> 8 nodes/wave (no shfl, non-divergent fast softplus epilogue);
//     agg1 -> 4x unroll (8 gather chains in flight).

#define N_NODES 50000
#define IN_DIM 512
#define HID 256
#define NCLS 64

typedef unsigned short u16;
typedef unsigned int u32;
typedef __attribute__((ext_vector_type(8))) short short8;
typedef __attribute__((ext_vector_type(4))) float float4_t;

__device__ __forceinline__ float bf_lo(u32 v) {
    u32 u = v << 16; float f; __builtin_memcpy(&f, &u, 4); return f;
}
__device__ __forceinline__ float bf_hi(u32 v) {
    u32 u = v & 0xffff0000u; float f; __builtin_memcpy(&f, &u, 4); return f;
}
__device__ __forceinline__ u16 f2bf(float f) {   // RNE float->bf16
    u32 u; __builtin_memcpy(&u, &f, 4);
    return (u16)((u + 0x7fffu + ((u >> 16) & 1u)) >> 16);
}
__device__ __forceinline__ void acc8(float* acc, uint4 v, float w) {
    acc[0] += w * bf_lo(v.x); acc[1] += w * bf_hi(v.x);
    acc[2] += w * bf_lo(v.y); acc[3] += w * bf_hi(v.y);
    acc[4] += w * bf_lo(v.z); acc[5] += w * bf_hi(v.z);
    acc[6] += w * bf_lo(v.w); acc[7] += w * bf_hi(v.w);
}

// ---------------- graph prep ----------------
__global__ void init_kernel(int* __restrict__ cnt, int* __restrict__ cursor, int n) {
    int i = blockIdx.x * blockDim.x + threadIdx.x;
    if (i < n) { cnt[i] = 0; cursor[i] = 0; }
}

__global__ void count_kernel(const int* __restrict__ dst, int* __restrict__ cnt, int E) {
    int e = blockIdx.x * blockDim.x + threadIdx.x;
    if (e < E) atomicAdd(&cnt[dst[e]], 1);
}

// s1: per-block reduce of cnt -> blocksum; fused dinv = rsqrt(cnt+1).
__global__ __launch_bounds__(256) void s1_kernel(const int* __restrict__ cnt,
                                                 int* __restrict__ blocksum,
                                                 float* __restrict__ dinv, int n) {
    int tid = threadIdx.x;
    int i = blockIdx.x * 256 + tid;
    int c = (i < n) ? cnt[i] : 0;
    if (i < n) dinv[i] = rsqrtf((float)(c + 1));  // +1 self-loop
    __shared__ int s[256];
    s[tid] = c;
    __syncthreads();
    for (int off = 128; off > 0; off >>= 1) {
        if (tid < off) s[tid] += s[tid + off];
        __syncthreads();
    }
    if (tid == 0) blocksum[blockIdx.x] = s[0];
}

// s2: single block scans the <=256 block sums -> exclusive block offsets.
__global__ __launch_bounds__(256) void s2_kernel(const int* __restrict__ blocksum,
                                                 int* __restrict__ blockoff, int nb) {
    int tid = threadIdx.x;
    int v = (tid < nb) ? blocksum[tid] : 0;
    __shared__ int s[256];
    s[tid] = v;
    __syncthreads();
    for (int off = 1; off < 256; off <<= 1) {
        int a = (tid >= off) ? s[tid - off] : 0;
        __syncthreads();
        s[tid] += a;
        __syncthreads();
    }
    blockoff[tid] = (tid == 0) ? 0 : s[tid - 1];
}

// s3: block-local exclusive scan + block offset -> row_ptr[0..n].
__global__ __launch_bounds__(256) void s3_kernel(const int* __restrict__ cnt,
                                                 const int* __restrict__ blockoff,
                                                 int* __restrict__ row_ptr, int n) {
    int tid = threadIdx.x;
    int i = blockIdx.x * 256 + tid;
    int c = (i < n) ? cnt[i] : 0;
    __shared__ int s[256];
    s[tid] = c;
    __syncthreads();
    for (int off = 1; off < 256; off <<= 1) {
        int a = (tid >= off) ? s[tid - off] : 0;
        __syncthreads();
        s[tid] += a;
        __syncthreads();
    }
    if (i <= n) row_ptr[i] = blockoff[blockIdx.x] + s[tid] - c;
}

__global__ void fill_kernel(const int* __restrict__ src, const int* __restrict__ dst,
                            const int* __restrict__ row_ptr, int* __restrict__ cursor,
                            int* __restrict__ csr_src, int E) {
    int e = blockIdx.x * blockDim.x + threadIdx.x;
    if (e >= E) return;
    int d = dst[e];
    int pos = row_ptr[d] + atomicAdd(&cursor[d], 1);
    csr_src[pos] = src[e];
}

// ---------------- casts ----------------
__global__ __launch_bounds__(256) void cast_bf16_kernel(const float* __restrict__ in,
                                                        u16* __restrict__ out, int n4) {
    int i = blockIdx.x * 256 + threadIdx.x;
    if (i >= n4) return;
    float4 v = ((const float4*)in)[i];
    ushort4 o = make_ushort4(f2bf(v.x), f2bf(v.y), f2bf(v.z), f2bf(v.w));
    ((ushort4*)out)[i] = o;
}

// Wt[n][k] = bf16(W[k][n]);  W is [K,N] row-major, Wt is [N,K] row-major.
__global__ __launch_bounds__(256) void tcast_kernel(const float* __restrict__ W,
                                                    u16* __restrict__ Wt, int K, int N) {
    int idx = blockIdx.x * 256 + threadIdx.x;
    if (idx >= K * N) return;
    int n = idx / K, k = idx - n * K;
    Wt[idx] = f2bf(W[k * N + n]);
}

// ---------------- bf16 MFMA GEMM ----------------
// C[M,N] = A[M,K] @ Bt[N,K]^T, all bf16 (u16), fp32 accumulate, bf16 out.
// 256 threads = 4 waves; per-wave 64x64 via 4x4 of 16x16x32 MFMA. BK=32.
template <int BM, int BN, int K, int N>
__global__ __launch_bounds__(256) void mfma_gemm_kernel(const u16* __restrict__ A,
                                                        const u16* __restrict__ Bt,
                                                        u16* __restrict__ C, int M) {
    constexpr int WCOLS = (BN >= 128) ? 2 : 1;
    constexpr int WROWS = 4 / WCOLS;
    static_assert(WROWS * 64 == BM && WCOLS * 64 == BN, "wave tiling mismatch");
    constexpr int LDSA = BM * 32;
    __shared__ u16 lds[LDSA + BN * 32];

    const int tid = threadIdx.x;
    const int wave = tid >> 6, lane = tid & 63;
    const int wm = wave / WCOLS, wn = wave % WCOLS;
    const int quad = lane >> 4, l15 = lane & 15;
    const int row0 = blockIdx.y * BM;
    const int col0 = blockIdx.x * BN;

    float4_t acc[4][4];
#pragma unroll
    for (int mi = 0; mi < 4; mi++)
#pragma unroll
        for (int ni = 0; ni < 4; ni++) {
            float4_t z = {0.f, 0.f, 0.f, 0.f};
            acc[mi][ni] = z;
        }

    for (int k0 = 0; k0 < K; k0 += 32) {
#pragma unroll
        for (int i = 0; i < BM / 64; i++) {
            int c = tid + i * 256;
            int r = c >> 2;
            int gr = row0 + r;
            gr = gr < M ? gr : M - 1;
            const u16* gp = A + (long)gr * K + k0 + (c & 3) * 8;
            u16* lp = lds + c * 8;
            __builtin_amdgcn_global_load_lds((const __attribute__((address_space(1))) u32*)gp,
                                             (__attribute__((address_space(3))) u32*)lp,
                                             16, 0, 0);
        }
#pragma unroll
        for (int i = 0; i < BN / 64; i++) {
            int c = tid + i * 256;
            int r = c >> 2;
            const u16* gp = Bt + (long)(col0 + r) * K + k0 + (c & 3) * 8;
            u16* lp = lds + LDSA + c * 8;
            __builtin_amdgcn_global_load_lds((const __attribute__((address_space(1))) u32*)gp,
                                             (__attribute__((address_space(3))) u32*)lp,
                                             16, 0, 0);
        }
        __syncthreads();

        short8 af[4], bfr[4];
#pragma unroll
        for (int mi = 0; mi < 4; mi++)
            af[mi] = *(const short8*)(lds + (wm * 64 + mi * 16 + l15) * 32 + quad * 8);
#pragma unroll
        for (int ni = 0; ni < 4; ni++)
            bfr[ni] = *(const short8*)(lds + LDSA + (wn * 64 + ni * 16 + l15) * 32 + quad * 8);
#pragma unroll
        for (int mi = 0; mi < 4; mi++)
#pragma unroll
            for (int ni = 0; ni < 4; ni++)
                acc[mi][ni] = __builtin_amdgcn_mfma_f32_16x16x32_bf16(af[mi], bfr[ni],
                                                                      acc[mi][ni], 0, 0, 0);
        __syncthreads();
    }

#pragma unroll
    for (int mi = 0; mi < 4; mi++) {
#pragma unroll
        for (int r = 0; r < 4; r++) {
            int row = row0 + wm * 64 + mi * 16 + quad * 4 + r;
            if (row < M) {
#pragma unroll
                for (int ni = 0; ni < 4; ni++) {
                    int col = col0 + wn * 64 + ni * 16 + l15;
                    C[(long)row * N + col] = f2bf(acc[mi][ni][r]);
                }
            }
        }
    }
}

// ---------------- agg1: wide rows (FEAT=256), one node per wave ----------------
// LPE=32 lanes cover a 512B row with uint4; G=2 edge groups; unroll x4 -> 8
// gather chains in flight. shfl_xor(32) combine; epilogue on lanes<32.
__global__ __launch_bounds__(256) void agg_wide_kernel(const u16* __restrict__ t,
                                                       const int* __restrict__ row_ptr,
                                                       const int* __restrict__ csr_src,
                                                       const float* __restrict__ dinv,
                                                       const float* __restrict__ bias,
                                                       float* __restrict__ out_f,
                                                       u16* __restrict__ out_bf, int n) {
    constexpr int FEAT = 256;
    int node = (blockIdx.x * blockDim.x + threadIdx.x) >> 6;
    int lane = threadIdx.x & 63;
    if (node >= n) return;
    const int g = lane >> 5;       // edge group 0..1
    const int r = lane & 31;       // lane within row
    float acc[8] = {};
    const int beg = row_ptr[node], end = row_ptr[node + 1];
    int e = beg;
    for (; e + 8 <= end; e += 8) {
        int s[4]; float w[4]; uint4 v[4];
#pragma unroll
        for (int u = 0; u < 4; u++) s[u] = csr_src[e + u * 2 + g];
#pragma unroll
        for (int u = 0; u < 4; u++) w[u] = dinv[s[u]];
#pragma unroll
        for (int u = 0; u < 4; u++) v[u] = *(const uint4*)(t + (long)s[u] * FEAT + r * 8);
#pragma unroll
        for (int u = 0; u < 4; u++) acc8(acc, v[u], w[u]);
    }
    for (; e < end; e += 2) {
        int ee = e + g;
        if (ee < end) {
            int s = csr_src[ee];
            float w = dinv[s];
            uint4 v = *(const uint4*)(t + (long)s * FEAT + r * 8);
            acc8(acc, v, w);
        }
    }
#pragma unroll
    for (int j = 0; j < 8; j++) acc[j] += __shfl_xor(acc[j], 32, 64);

    if (lane < 32) {
        const float di = dinv[node];
        uint4 sv = *(const uint4*)(t + (long)node * FEAT + lane * 8);
        float self[8] = {bf_lo(sv.x), bf_hi(sv.x), bf_lo(sv.y), bf_hi(sv.y),
                         bf_lo(sv.z), bf_hi(sv.z), bf_lo(sv.w), bf_hi(sv.w)};
        float4 b0 = *(const float4*)(bias + lane * 8);
        float4 b1 = *(const float4*)(bias + lane * 8 + 4);
        float bb[8] = {b0.x, b0.y, b0.z, b0.w, b1.x, b1.y, b1.z, b1.w};
        float rv[8];
#pragma unroll
        for (int j = 0; j < 8; j++)
            rv[j] = fmaxf(di * (acc[j] + di * self[j]) + bb[j], 0.f);  // relu
        long base = (long)node * FEAT + lane * 8;
        *(float4*)(out_f + base) = make_float4(rv[0], rv[1], rv[2], rv[3]);
        *(float4*)(out_f + base + 4) = make_float4(rv[4], rv[5], rv[6], rv[7]);
        uint4 o;
        o.x = (u32)f2bf(rv[0]) | ((u32)f2bf(rv[1]) << 16);
        o.y = (u32)f2bf(rv[2]) | ((u32)f2bf(rv[3]) << 16);
        o.z = (u32)f2bf(rv[4]) | ((u32)f2bf(rv[5]) << 16);
        o.w = (u32)f2bf(rv[6]) | ((u32)f2bf(rv[7]) << 16);
        *(uint4*)(out_bf + base) = o;
    }
}

// ---------------- agg2: narrow rows (FEAT=64), 8 nodes per wave ----------------
// 8 lanes x 16B cover a 128B row; each 8-lane group owns one node; 2 edges in
// flight per group. No shuffles; epilogue on all 64 lanes (fast softplus);
// stores 2KB contiguous per wave.
__global__ __launch_bounds__(256) void agg_n8_kernel(const u16* __restrict__ t,
                                                     const int* __restrict__ row_ptr,
                                                     const int* __restrict__ csr_src,
                                                     const float* __restrict__ dinv,
                                                     const float* __restrict__ bias,
                                                     float* __restrict__ out_f, int n) {
    constexpr int FEAT = 64;
    const int wid = (blockIdx.x * blockDim.x + threadIdx.x) >> 6;
    const int lane = threadIdx.x & 63;
    const int g = lane >> 3;   // node group 0..7
    const int r = lane & 7;    // lane within row
    const int node = wid * 8 + g;
    const bool valid = node < n;
    const int nd = valid ? node : (n - 1);
    const int beg = row_ptr[nd];
    const int deg = valid ? (row_ptr[nd + 1] - beg) : 0;
    float acc[8] = {};
    for (int e = 0;; e += 2) {
        bool a0 = e < deg, a1 = e + 1 < deg;
        if (!__any(a0)) break;
        int s0 = a0 ? csr_src[beg + e] : 0;
        int s1 = a1 ? csr_src[beg + e + 1] : 0;
        float w0 = a0 ? dinv[s0] : 0.f;
        float w1 = a1 ? dinv[s1] : 0.f;
        uint4 v0 = *(const uint4*)(t + (long)s0 * FEAT + r * 8);
        uint4 v1 = *(const uint4*)(t + (long)s1 * FEAT + r * 8);
        acc8(acc, v0, w0);   // w=0 kills garbage rows (values finite)
        acc8(acc, v1, w1);
    }
    const float di = dinv[nd];
    uint4 sv = *(const uint4*)(t + (long)nd * FEAT + r * 8);
    float self[8] = {bf_lo(sv.x), bf_hi(sv.x), bf_lo(sv.y), bf_hi(sv.y),
                     bf_lo(sv.z), bf_hi(sv.z), bf_lo(sv.w), bf_hi(sv.w)};
    float4 b0 = *(const float4*)(bias + r * 8);
    float4 b1 = *(const float4*)(bias + r * 8 + 4);
    float bb[8] = {b0.x, b0.y, b0.z, b0.w, b1.x, b1.y, b1.z, b1.w};
    float rv[8];
#pragma unroll
    for (int j = 0; j < 8; j++) {
        float v = di * (acc[j] + di * self[j]) + bb[j];
        // fast softplus: max(v,0) + ln(1+exp(-|v|)) via v_exp/v_log
        rv[j] = fmaxf(v, 0.f) + __logf(1.f + __expf(-fabsf(v)));
    }
    if (valid) {
        long base = (long)nd * FEAT + r * 8;
        *(float4*)(out_f + base) = make_float4(rv[0], rv[1], rv[2], rv[3]);
        *(float4*)(out_f + base + 4) = make_float4(rv[4], rv[5], rv[6], rv[7]);
    }
}

extern "C" void kernel_launch(void* const* d_in, const int* in_sizes, int n_in,
                              void* d_out, int out_size, void* d_ws, size_t ws_size,
                              hipStream_t stream) {
    const float* x  = (const float*)d_in[0];
    const int*   ei = (const int*)d_in[1];
    const float* W1 = (const float*)d_in[2];
    const float* b1 = (const float*)d_in[3];
    const float* W2 = (const float*)d_in[4];
    const float* b2 = (const float*)d_in[5];

    float* evidence = (float*)d_out;                        // [50000, 64]
    float* h        = (float*)d_out + (long)N_NODES * NCLS; // [50000, 256]

    const int E = in_sizes[1] / 2;
    const int* src = ei;
    const int* dst = ei + E;

    const int NB = (N_NODES + 255) / 256;  // 196 scan blocks

    // workspace carve-up (16B-aligned regions)
    char* w = (char*)d_ws;
    int*   cnt      = (int*)w;  w += 50048 * 4;
    int*   cursor   = (int*)w;  w += 50048 * 4;
    int*   row_ptr  = (int*)w;  w += 50064 * 4;
    float* dinv     = (float*)w; w += 50048 * 4;
    int*   blocksum = (int*)w;  w += 256 * 4;
    int*   blockoff = (int*)w;  w += 256 * 4;
    int*   csr_src  = (int*)w;  w += 800000 * 4;
    u16*   xbf      = (u16*)w;  w += (long)N_NODES * IN_DIM * 2;  // reused as h_bf
    u16*   w1t      = (u16*)w;  w += IN_DIM * HID * 2;
    u16*   w2t      = (u16*)w;  w += HID * NCLS * 2;
    u16*   t1bf     = (u16*)w;  w += (long)N_NODES * HID * 2;     // reused as t2_bf
    u16*   hbf      = xbf;
    u16*   t2bf     = t1bf;

    // graph prep
    init_kernel<<<NB, 256, 0, stream>>>(cnt, cursor, N_NODES);
    count_kernel<<<(E + 255) / 256, 256, 0, stream>>>(dst, cnt, E);
    s1_kernel<<<NB, 256, 0, stream>>>(cnt, blocksum, dinv, N_NODES);
    s2_kernel<<<1, 256, 0, stream>>>(blocksum, blockoff, NB);
    s3_kernel<<<NB, 256, 0, stream>>>(cnt, blockoff, row_ptr, N_NODES);
    fill_kernel<<<(E + 255) / 256, 256, 0, stream>>>(src, dst, row_ptr, cursor, csr_src, E);

    // casts
    cast_bf16_kernel<<<(N_NODES * IN_DIM / 4 + 255) / 256, 256, 0, stream>>>(
        x, xbf, N_NODES * IN_DIM / 4);
    tcast_kernel<<<(IN_DIM * HID + 255) / 256, 256, 0, stream>>>(W1, w1t, IN_DIM, HID);
    tcast_kernel<<<(HID * NCLS + 255) / 256, 256, 0, stream>>>(W2, w2t, HID, NCLS);

    // layer 1: t1 = x @ W1 (bf16 MFMA); h = relu(agg(t1) + b1), also h_bf
    {
        dim3 grid(HID / 128, (N_NODES + 127) / 128);
        mfma_gemm_kernel<128, 128, IN_DIM, HID><<<grid, 256, 0, stream>>>(xbf, w1t, t1bf, N_NODES);
    }
    agg_wide_kernel<<<(N_NODES * 64 + 255) / 256, 256, 0, stream>>>(
        t1bf, row_ptr, csr_src, dinv, b1, h, hbf, N_NODES);

    // layer 2: t2 = h @ W2 (bf16 MFMA); evidence = softplus(agg(t2) + b2)
    {
        dim3 grid(NCLS / 64, (N_NODES + 255) / 256);
        mfma_gemm_kernel<256, 64, HID, NCLS><<<grid, 256, 0, stream>>>(hbf, w2t, t2bf, N_NODES);
    }
    {
        int waves = (N_NODES + 7) / 8;                 // 6250 waves
        int blocks = (waves + 3) / 4;                  // 4 waves per block
        agg_n8_kernel<<<blocks, 256, 0, stream>>>(
            t2bf, row_ptr, csr_src, dinv, b2, evidence, N_NODES);
    }
}

// Round 7
// 408.974 us; speedup vs baseline: 2.2925x; 1.0047x over previous
//
#include <hip/hip_runtime.h>

// EvidentialGNN: 2-layer GCN. evidence = softplus(gcn2(relu(gcn1(x)))).
// Outputs concatenated: (evidence[50000,64], h[50000,256]).
// R7: agg_wide tiered unroll 16/8/2 (16 gather chains in flight for deg>=16);
//     agg_n8 4-edge unroll; s2 fused into s3 (one fewer launch).

#define N_NODES 50000
#define IN_DIM 512
#define HID 256
#define NCLS 64

typedef unsigned short u16;
typedef unsigned int u32;
typedef __attribute__((ext_vector_type(8))) short short8;
typedef __attribute__((ext_vector_type(4))) float float4_t;

__device__ __forceinline__ float bf_lo(u32 v) {
    u32 u = v << 16; float f; __builtin_memcpy(&f, &u, 4); return f;
}
__device__ __forceinline__ float bf_hi(u32 v) {
    u32 u = v & 0xffff0000u; float f; __builtin_memcpy(&f, &u, 4); return f;
}
__device__ __forceinline__ u16 f2bf(float f) {   // RNE float->bf16
    u32 u; __builtin_memcpy(&u, &f, 4);
    return (u16)((u + 0x7fffu + ((u >> 16) & 1u)) >> 16);
}
__device__ __forceinline__ void acc8(float* acc, uint4 v, float w) {
    acc[0] += w * bf_lo(v.x); acc[1] += w * bf_hi(v.x);
    acc[2] += w * bf_lo(v.y); acc[3] += w * bf_hi(v.y);
    acc[4] += w * bf_lo(v.z); acc[5] += w * bf_hi(v.z);
    acc[6] += w * bf_lo(v.w); acc[7] += w * bf_hi(v.w);
}

// ---------------- graph prep ----------------
__global__ void init_kernel(int* __restrict__ cnt, int* __restrict__ cursor, int n) {
    int i = blockIdx.x * blockDim.x + threadIdx.x;
    if (i < n) { cnt[i] = 0; cursor[i] = 0; }
}

__global__ void count_kernel(const int* __restrict__ dst, int* __restrict__ cnt, int E) {
    int e = blockIdx.x * blockDim.x + threadIdx.x;
    if (e < E) atomicAdd(&cnt[dst[e]], 1);
}

// s1: per-block reduce of cnt -> blocksum; fused dinv = rsqrt(cnt+1).
__global__ __launch_bounds__(256) void s1_kernel(const int* __restrict__ cnt,
                                                 int* __restrict__ blocksum,
                                                 float* __restrict__ dinv, int n) {
    int tid = threadIdx.x;
    int i = blockIdx.x * 256 + tid;
    int c = (i < n) ? cnt[i] : 0;
    if (i < n) dinv[i] = rsqrtf((float)(c + 1));  // +1 self-loop
    __shared__ int s[256];
    s[tid] = c;
    __syncthreads();
    for (int off = 128; off > 0; off >>= 1) {
        if (tid < off) s[tid] += s[tid + off];
        __syncthreads();
    }
    if (tid == 0) blocksum[blockIdx.x] = s[0];
}

// s3 (fused s2): every block scans the <=256 block sums in LDS to get its own
// offset, then does the block-local exclusive scan -> row_ptr[0..n].
__global__ __launch_bounds__(256) void s3_kernel(const int* __restrict__ cnt,
                                                 const int* __restrict__ blocksum,
                                                 int* __restrict__ row_ptr, int n, int nb) {
    __shared__ int bs[256];
    __shared__ int s[256];
    int tid = threadIdx.x;
    int v = (tid < nb) ? blocksum[tid] : 0;
    bs[tid] = v;
    __syncthreads();
    for (int off = 1; off < 256; off <<= 1) {
        int a = (tid >= off) ? bs[tid - off] : 0;
        __syncthreads();
        bs[tid] += a;
        __syncthreads();
    }
    int boff = (blockIdx.x == 0) ? 0 : bs[blockIdx.x - 1];
    int i = blockIdx.x * 256 + tid;
    int c = (i < n) ? cnt[i] : 0;
    s[tid] = c;
    __syncthreads();
    for (int off = 1; off < 256; off <<= 1) {
        int a = (tid >= off) ? s[tid - off] : 0;
        __syncthreads();
        s[tid] += a;
        __syncthreads();
    }
    if (i <= n) row_ptr[i] = boff + s[tid] - c;
}

__global__ void fill_kernel(const int* __restrict__ src, const int* __restrict__ dst,
                            const int* __restrict__ row_ptr, int* __restrict__ cursor,
                            int* __restrict__ csr_src, int E) {
    int e = blockIdx.x * blockDim.x + threadIdx.x;
    if (e >= E) return;
    int d = dst[e];
    int pos = row_ptr[d] + atomicAdd(&cursor[d], 1);
    csr_src[pos] = src[e];
}

// ---------------- casts ----------------
__global__ __launch_bounds__(256) void cast_bf16_kernel(const float* __restrict__ in,
                                                        u16* __restrict__ out, int n4) {
    int i = blockIdx.x * 256 + threadIdx.x;
    if (i >= n4) return;
    float4 v = ((const float4*)in)[i];
    ushort4 o = make_ushort4(f2bf(v.x), f2bf(v.y), f2bf(v.z), f2bf(v.w));
    ((ushort4*)out)[i] = o;
}

// Wt[n][k] = bf16(W[k][n]);  W is [K,N] row-major, Wt is [N,K] row-major.
__global__ __launch_bounds__(256) void tcast_kernel(const float* __restrict__ W,
                                                    u16* __restrict__ Wt, int K, int N) {
    int idx = blockIdx.x * 256 + threadIdx.x;
    if (idx >= K * N) return;
    int n = idx / K, k = idx - n * K;
    Wt[idx] = f2bf(W[k * N + n]);
}

// ---------------- bf16 MFMA GEMM ----------------
// C[M,N] = A[M,K] @ Bt[N,K]^T, all bf16 (u16), fp32 accumulate, bf16 out.
// 256 threads = 4 waves; per-wave 64x64 via 4x4 of 16x16x32 MFMA. BK=32.
template <int BM, int BN, int K, int N>
__global__ __launch_bounds__(256) void mfma_gemm_kernel(const u16* __restrict__ A,
                                                        const u16* __restrict__ Bt,
                                                        u16* __restrict__ C, int M) {
    constexpr int WCOLS = (BN >= 128) ? 2 : 1;
    constexpr int WROWS = 4 / WCOLS;
    static_assert(WROWS * 64 == BM && WCOLS * 64 == BN, "wave tiling mismatch");
    constexpr int LDSA = BM * 32;
    __shared__ u16 lds[LDSA + BN * 32];

    const int tid = threadIdx.x;
    const int wave = tid >> 6, lane = tid & 63;
    const int wm = wave / WCOLS, wn = wave % WCOLS;
    const int quad = lane >> 4, l15 = lane & 15;
    const int row0 = blockIdx.y * BM;
    const int col0 = blockIdx.x * BN;

    float4_t acc[4][4];
#pragma unroll
    for (int mi = 0; mi < 4; mi++)
#pragma unroll
        for (int ni = 0; ni < 4; ni++) {
            float4_t z = {0.f, 0.f, 0.f, 0.f};
            acc[mi][ni] = z;
        }

    for (int k0 = 0; k0 < K; k0 += 32) {
#pragma unroll
        for (int i = 0; i < BM / 64; i++) {
            int c = tid + i * 256;
            int r = c >> 2;
            int gr = row0 + r;
            gr = gr < M ? gr : M - 1;
            const u16* gp = A + (long)gr * K + k0 + (c & 3) * 8;
            u16* lp = lds + c * 8;
            __builtin_amdgcn_global_load_lds((const __attribute__((address_space(1))) u32*)gp,
                                             (__attribute__((address_space(3))) u32*)lp,
                                             16, 0, 0);
        }
#pragma unroll
        for (int i = 0; i < BN / 64; i++) {
            int c = tid + i * 256;
            int r = c >> 2;
            const u16* gp = Bt + (long)(col0 + r) * K + k0 + (c & 3) * 8;
            u16* lp = lds + LDSA + c * 8;
            __builtin_amdgcn_global_load_lds((const __attribute__((address_space(1))) u32*)gp,
                                             (__attribute__((address_space(3))) u32*)lp,
                                             16, 0, 0);
        }
        __syncthreads();

        short8 af[4], bfr[4];
#pragma unroll
        for (int mi = 0; mi < 4; mi++)
            af[mi] = *(const short8*)(lds + (wm * 64 + mi * 16 + l15) * 32 + quad * 8);
#pragma unroll
        for (int ni = 0; ni < 4; ni++)
            bfr[ni] = *(const short8*)(lds + LDSA + (wn * 64 + ni * 16 + l15) * 32 + quad * 8);
#pragma unroll
        for (int mi = 0; mi < 4; mi++)
#pragma unroll
            for (int ni = 0; ni < 4; ni++)
                acc[mi][ni] = __builtin_amdgcn_mfma_f32_16x16x32_bf16(af[mi], bfr[ni],
                                                                      acc[mi][ni], 0, 0, 0);
        __syncthreads();
    }

#pragma unroll
    for (int mi = 0; mi < 4; mi++) {
#pragma unroll
        for (int r = 0; r < 4; r++) {
            int row = row0 + wm * 64 + mi * 16 + quad * 4 + r;
            if (row < M) {
#pragma unroll
                for (int ni = 0; ni < 4; ni++) {
                    int col = col0 + wn * 64 + ni * 16 + l15;
                    C[(long)row * N + col] = f2bf(acc[mi][ni][r]);
                }
            }
        }
    }
}

// ---------------- agg1: wide rows (FEAT=256), one node per wave ----------------
// 32 lanes cover a 512B row with uint4; 2 edge groups; tiered unroll 16/8/2 ->
// up to 16 gather chains in flight. shfl_xor(32) combine; epilogue on lanes<32.
__global__ __launch_bounds__(256) void agg_wide_kernel(const u16* __restrict__ t,
                                                       const int* __restrict__ row_ptr,
                                                       const int* __restrict__ csr_src,
                                                       const float* __restrict__ dinv,
                                                       const float* __restrict__ bias,
                                                       float* __restrict__ out_f,
                                                       u16* __restrict__ out_bf, int n) {
    constexpr int FEAT = 256;
    int node = (blockIdx.x * blockDim.x + threadIdx.x) >> 6;
    int lane = threadIdx.x & 63;
    if (node >= n) return;
    const int g = lane >> 5;       // edge group 0..1
    const int r = lane & 31;       // lane within row
    float acc[8] = {};
    const int beg = row_ptr[node], end = row_ptr[node + 1];
    int e = beg;
    for (; e + 16 <= end; e += 16) {   // 8 edges per group, 16 chains in flight
        int s[8]; float w[8]; uint4 v[8];
#pragma unroll
        for (int u = 0; u < 8; u++) s[u] = csr_src[e + u * 2 + g];
#pragma unroll
        for (int u = 0; u < 8; u++) w[u] = dinv[s[u]];
#pragma unroll
        for (int u = 0; u < 8; u++) v[u] = *(const uint4*)(t + (long)s[u] * FEAT + r * 8);
#pragma unroll
        for (int u = 0; u < 8; u++) acc8(acc, v[u], w[u]);
    }
    for (; e + 8 <= end; e += 8) {
        int s[4]; float w[4]; uint4 v[4];
#pragma unroll
        for (int u = 0; u < 4; u++) s[u] = csr_src[e + u * 2 + g];
#pragma unroll
        for (int u = 0; u < 4; u++) w[u] = dinv[s[u]];
#pragma unroll
        for (int u = 0; u < 4; u++) v[u] = *(const uint4*)(t + (long)s[u] * FEAT + r * 8);
#pragma unroll
        for (int u = 0; u < 4; u++) acc8(acc, v[u], w[u]);
    }
    for (; e < end; e += 2) {
        int ee = e + g;
        if (ee < end) {
            int s = csr_src[ee];
            float w = dinv[s];
            uint4 v = *(const uint4*)(t + (long)s * FEAT + r * 8);
            acc8(acc, v, w);
        }
    }
#pragma unroll
    for (int j = 0; j < 8; j++) acc[j] += __shfl_xor(acc[j], 32, 64);

    if (lane < 32) {
        const float di = dinv[node];
        uint4 sv = *(const uint4*)(t + (long)node * FEAT + lane * 8);
        float self[8] = {bf_lo(sv.x), bf_hi(sv.x), bf_lo(sv.y), bf_hi(sv.y),
                         bf_lo(sv.z), bf_hi(sv.z), bf_lo(sv.w), bf_hi(sv.w)};
        float4 b0 = *(const float4*)(bias + lane * 8);
        float4 b1 = *(const float4*)(bias + lane * 8 + 4);
        float bb[8] = {b0.x, b0.y, b0.z, b0.w, b1.x, b1.y, b1.z, b1.w};
        float rv[8];
#pragma unroll
        for (int j = 0; j < 8; j++)
            rv[j] = fmaxf(di * (acc[j] + di * self[j]) + bb[j], 0.f);  // relu
        long base = (long)node * FEAT + lane * 8;
        *(float4*)(out_f + base) = make_float4(rv[0], rv[1], rv[2], rv[3]);
        *(float4*)(out_f + base + 4) = make_float4(rv[4], rv[5], rv[6], rv[7]);
        uint4 o;
        o.x = (u32)f2bf(rv[0]) | ((u32)f2bf(rv[1]) << 16);
        o.y = (u32)f2bf(rv[2]) | ((u32)f2bf(rv[3]) << 16);
        o.z = (u32)f2bf(rv[4]) | ((u32)f2bf(rv[5]) << 16);
        o.w = (u32)f2bf(rv[6]) | ((u32)f2bf(rv[7]) << 16);
        *(uint4*)(out_bf + base) = o;
    }
}

// ---------------- agg2: narrow rows (FEAT=64), 8 nodes per wave ----------------
// 8 lanes x 16B cover a 128B row; each 8-lane group owns one node; 4 edges in
// flight per group. No shuffles; epilogue on all 64 lanes (fast softplus).
__global__ __launch_bounds__(256) void agg_n8_kernel(const u16* __restrict__ t,
                                                     const int* __restrict__ row_ptr,
                                                     const int* __restrict__ csr_src,
                                                     const float* __restrict__ dinv,
                                                     const float* __restrict__ bias,
                                                     float* __restrict__ out_f, int n) {
    constexpr int FEAT = 64;
    const int wid = (blockIdx.x * blockDim.x + threadIdx.x) >> 6;
    const int lane = threadIdx.x & 63;
    const int g = lane >> 3;   // node group 0..7
    const int r = lane & 7;    // lane within row
    const int node = wid * 8 + g;
    const bool valid = node < n;
    const int nd = valid ? node : (n - 1);
    const int beg = row_ptr[nd];
    const int deg = valid ? (row_ptr[nd + 1] - beg) : 0;
    float acc[8] = {};
    for (int e = 0;; e += 4) {
        if (!__any(e < deg)) break;
        int s[4]; float w[4]; uint4 v[4];
#pragma unroll
        for (int u = 0; u < 4; u++) {
            bool a = (e + u) < deg;
            s[u] = a ? csr_src[beg + e + u] : 0;
            w[u] = a ? 0.f : 0.f;  // placeholder, set below after gather
            w[u] = a ? 1.f : 0.f;
        }
#pragma unroll
        for (int u = 0; u < 4; u++) w[u] = w[u] * dinv[s[u]];
#pragma unroll
        for (int u = 0; u < 4; u++) v[u] = *(const uint4*)(t + (long)s[u] * FEAT + r * 8);
#pragma unroll
        for (int u = 0; u < 4; u++) acc8(acc, v[u], w[u]);  // w=0 kills garbage rows
    }
    const float di = dinv[nd];
    uint4 sv = *(const uint4*)(t + (long)nd * FEAT + r * 8);
    float self[8] = {bf_lo(sv.x), bf_hi(sv.x), bf_lo(sv.y), bf_hi(sv.y),
                     bf_lo(sv.z), bf_hi(sv.z), bf_lo(sv.w), bf_hi(sv.w)};
    float4 b0 = *(const float4*)(bias + r * 8);
    float4 b1 = *(const float4*)(bias + r * 8 + 4);
    float bb[8] = {b0.x, b0.y, b0.z, b0.w, b1.x, b1.y, b1.z, b1.w};
    float rv[8];
#pragma unroll
    for (int j = 0; j < 8; j++) {
        float v = di * (acc[j] + di * self[j]) + bb[j];
        // fast softplus: max(v,0) + ln(1+exp(-|v|)) via v_exp/v_log
        rv[j] = fmaxf(v, 0.f) + __logf(1.f + __expf(-fabsf(v)));
    }
    if (valid) {
        long base = (long)nd * FEAT + r * 8;
        *(float4*)(out_f + base) = make_float4(rv[0], rv[1], rv[2], rv[3]);
        *(float4*)(out_f + base + 4) = make_float4(rv[4], rv[5], rv[6], rv[7]);
    }
}

extern "C" void kernel_launch(void* const* d_in, const int* in_sizes, int n_in,
                              void* d_out, int out_size, void* d_ws, size_t ws_size,
                              hipStream_t stream) {
    const float* x  = (const float*)d_in[0];
    const int*   ei = (const int*)d_in[1];
    const float* W1 = (const float*)d_in[2];
    const float* b1 = (const float*)d_in[3];
    const float* W2 = (const float*)d_in[4];
    const float* b2 = (const float*)d_in[5];

    float* evidence = (float*)d_out;                        // [50000, 64]
    float* h        = (float*)d_out + (long)N_NODES * NCLS; // [50000, 256]

    const int E = in_sizes[1] / 2;
    const int* src = ei;
    const int* dst = ei + E;

    const int NB = (N_NODES + 255) / 256;  // 196 scan blocks

    // workspace carve-up (16B-aligned regions)
    char* w = (char*)d_ws;
    int*   cnt      = (int*)w;  w += 50048 * 4;
    int*   cursor   = (int*)w;  w += 50048 * 4;
    int*   row_ptr  = (int*)w;  w += 50064 * 4;
    float* dinv     = (float*)w; w += 50048 * 4;
    int*   blocksum = (int*)w;  w += 256 * 4;
    int*   csr_src  = (int*)w;  w += 800000 * 4;
    u16*   xbf      = (u16*)w;  w += (long)N_NODES * IN_DIM * 2;  // reused as h_bf
    u16*   w1t      = (u16*)w;  w += IN_DIM * HID * 2;
    u16*   w2t      = (u16*)w;  w += HID * NCLS * 2;
    u16*   t1bf     = (u16*)w;  w += (long)N_NODES * HID * 2;     // reused as t2_bf
    u16*   hbf      = xbf;
    u16*   t2bf     = t1bf;

    // graph prep
    init_kernel<<<NB, 256, 0, stream>>>(cnt, cursor, N_NODES);
    count_kernel<<<(E + 255) / 256, 256, 0, stream>>>(dst, cnt, E);
    s1_kernel<<<NB, 256, 0, stream>>>(cnt, blocksum, dinv, N_NODES);
    s3_kernel<<<NB, 256, 0, stream>>>(cnt, blocksum, row_ptr, N_NODES, NB);
    fill_kernel<<<(E + 255) / 256, 256, 0, stream>>>(src, dst, row_ptr, cursor, csr_src, E);

    // casts
    cast_bf16_kernel<<<(N_NODES * IN_DIM / 4 + 255) / 256, 256, 0, stream>>>(
        x, xbf, N_NODES * IN_DIM / 4);
    tcast_kernel<<<(IN_DIM * HID + 255) / 256, 256, 0, stream>>>(W1, w1t, IN_DIM, HID);
    tcast_kernel<<<(HID * NCLS + 255) / 256, 256, 0, stream>>>(W2, w2t, HID, NCLS);

    // layer 1: t1 = x @ W1 (bf16 MFMA); h = relu(agg(t1) + b1), also h_bf
    {
        dim3 grid(HID / 128, (N_NODES + 127) / 128);
        mfma_gemm_kernel<128, 128, IN_DIM, HID><<<grid, 256, 0, stream>>>(xbf, w1t, t1bf, N_NODES);
    }
    agg_wide_kernel<<<(N_NODES * 64 + 255) / 256, 256, 0, stream>>>(
        t1bf, row_ptr, csr_src, dinv, b1, h, hbf, N_NODES);

    // layer 2: t2 = h @ W2 (bf16 MFMA); evidence = softplus(agg(t2) + b2)
    {
        dim3 grid(NCLS / 64, (N_NODES + 255) / 256);
        mfma_gemm_kernel<256, 64, HID, NCLS><<<grid, 256, 0, stream>>>(hbf, w2t, t2bf, N_NODES);
    }
    {
        int waves = (N_NODES + 7) / 8;                 // 6250 waves
        int blocks = (waves + 3) / 4;                  // 4 waves per block
        agg_n8_kernel<<<blocks, 256, 0, stream>>>(
            t2bf, row_ptr, csr_src, dinv, b2, evidence, N_NODES);
    }
}